// Round 4
// baseline (542.107 us; speedup 1.0000x reference)
//
#include <hip/hip_runtime.h>

// LinearAttention: out[b,h,l,v] = rq[l]*rk[l]*V[l,v] / (rq[l]*cs[l] + EPS)
//   rq = rowsum(elu(Q)+1), rk = rowsum(elu(K)+1), cs = colsum(elu(K)+1)
// B=H=8 -> 64 (b,h) tiles, L=DK=1024, DV=64, fp32. Memory-bound.
// R1: 1024 blocks (50% occ cap) + VGPR=28 (serialized loads) -> 1.5 TB/s,
//     latency-bound. R2: 4096 blocks + 8 loads in flight, VGPR<=64.

#define EPS 1e-6f

constexpr int L   = 1024;
constexpr int DK  = 1024;
constexpr int DV  = 64;
constexpr int NBH = 64;           // B*H
constexpr int RPB = 16;           // rows per block (4 waves x 4 rows)

__device__ __forceinline__ float elup(float x) {
    // elu(x)+1 = x+1 (x>0), exp(x) (x<=0)
    return x > 0.0f ? x + 1.0f : __expf(x);
}

// Pass 1: stream Q,K once; rowsumQ/rowsumK per row, colsum(Kp) per (b,h).
// Grid 4096 blocks -> 8 blocks/CU (32 waves/CU). Wave w owns rows
// rb*16 + w*4 .. +3 (contiguous 16 KB per wave -> good prefetch/L2).
__global__ __launch_bounds__(256, 8) void reduce_kernel(
    const float* __restrict__ Q, const float* __restrict__ K,
    float* __restrict__ colsum, float* __restrict__ rowsumQ,
    float* __restrict__ rowsumK)
{
    const int bh   = blockIdx.x / (L / RPB);
    const int rb   = blockIdx.x % (L / RPB);
    const int wave = threadIdx.x >> 6;
    const int lane = threadIdx.x & 63;

    const size_t tile_base = (size_t)bh * L * DK;

    float4 cacc[4];
    #pragma unroll
    for (int i = 0; i < 4; ++i) cacc[i] = make_float4(0.f, 0.f, 0.f, 0.f);

    for (int j = 0; j < RPB / 4; ++j) {
        const int row = rb * RPB + wave * (RPB / 4) + j;
        const float* qp = Q + tile_base + (size_t)row * DK + lane * 4;
        const float* kp = K + tile_base + (size_t)row * DK + lane * 4;

        // Issue all 8 loads before touching any of them (MLP=8/wave).
        float4 q[4], k[4];
        #pragma unroll
        for (int i = 0; i < 4; ++i) q[i] = *(const float4*)(qp + i * 256);
        #pragma unroll
        for (int i = 0; i < 4; ++i) k[i] = *(const float4*)(kp + i * 256);

        float rq = 0.f, rk = 0.f;
        #pragma unroll
        for (int i = 0; i < 4; ++i) {
            const float q0 = elup(q[i].x), q1 = elup(q[i].y);
            const float q2 = elup(q[i].z), q3 = elup(q[i].w);
            const float k0 = elup(k[i].x), k1 = elup(k[i].y);
            const float k2 = elup(k[i].z), k3 = elup(k[i].w);
            rq += (q0 + q1) + (q2 + q3);
            rk += (k0 + k1) + (k2 + k3);
            cacc[i].x += k0; cacc[i].y += k1; cacc[i].z += k2; cacc[i].w += k3;
        }

        // Wave butterfly (lgkm chain; overlaps with next row's vmem loads).
        #pragma unroll
        for (int m = 32; m >= 1; m >>= 1) {
            rq += __shfl_xor(rq, m, 64);
            rk += __shfl_xor(rk, m, 64);
        }
        if (lane == 0) {
            rowsumQ[bh * L + row] = rq;
            rowsumK[bh * L + row] = rk;
        }
    }

    // Cross-wave column reduce: each wave dumps 1024 partials to its LDS
    // slice (float4, conflict-free), 256 threads fold 4 slices, atomicAdd
    // into L2-resident per-(b,h) colsum (4M f32 atomics total, 64/entry).
    __shared__ float scol[4 * DK];
    #pragma unroll
    for (int i = 0; i < 4; ++i) {
        *(float4*)&scol[wave * DK + i * 256 + lane * 4] = cacc[i];
    }
    __syncthreads();
    #pragma unroll
    for (int t = threadIdx.x; t < DK; t += 256) {
        const float s = scol[t] + scol[DK + t] + scol[2 * DK + t] + scol[3 * DK + t];
        atomicAdd(&colsum[bh * DK + t], s);
    }
}

// Pass 2: out = V * (rq*rk)/(rq*cs + EPS). One float4 per thread.
// colsum is indexed by l (k==l in this problem), so flat index == row.
__global__ __launch_bounds__(256) void finalize_kernel(
    const float* __restrict__ V, const float* __restrict__ colsum,
    const float* __restrict__ rowsumQ, const float* __restrict__ rowsumK,
    float* __restrict__ out)
{
    const int e4  = blockIdx.x * 256 + threadIdx.x; // group of 4 elems
    const int row = e4 >> 4;                        // DV/4 = 16 groups/row
    const float rq = rowsumQ[row];
    const float rk = rowsumK[row];
    const float cs = colsum[row];
    const float scale = rq * rk / (rq * cs + EPS);
    const float4 v = *(const float4*)(V + (size_t)e4 * 4);
    float4 o;
    o.x = v.x * scale; o.y = v.y * scale; o.z = v.z * scale; o.w = v.w * scale;
    *(float4*)(out + (size_t)e4 * 4) = o;
}

extern "C" void kernel_launch(void* const* d_in, const int* in_sizes, int n_in,
                              void* d_out, int out_size, void* d_ws, size_t ws_size,
                              hipStream_t stream) {
    const float* Q = (const float*)d_in[0];
    const float* K = (const float*)d_in[1];
    const float* V = (const float*)d_in[2];
    float* out = (float*)d_out;

    float* colsum  = (float*)d_ws;        // 64*1024 f32 = 256 KB
    float* rowsumQ = colsum + NBH * L;    // 256 KB
    float* rowsumK = rowsumQ + NBH * L;   // 256 KB

    hipMemsetAsync(colsum, 0, (size_t)NBH * DK * sizeof(float), stream);

    reduce_kernel<<<NBH * (L / RPB), 256, 0, stream>>>(
        Q, K, colsum, rowsumQ, rowsumK);

    finalize_kernel<<<(NBH * L * DV / 4) / 256, 256, 0, stream>>>(
        V, colsum, rowsumQ, rowsumK, out);
}

// Round 7
// 521.571 us; speedup vs baseline: 1.0394x; 1.0394x over previous
//
#include <hip/hip_runtime.h>

// LinearAttention: out[b,h,l,v] = rq[l]*rk[l]*V[l,v] / (rq[l]*cs[l] + EPS)
//   rq = rowsum(elu(Q)+1), rk = rowsum(elu(K)+1), cs = colsum(elu(K)+1)
// B=H=8 -> 64 (b,h) tiles, L=DK=1024, DV=64, fp32. Memory-bound.
// R1: 1024 blocks -> 43% occ, 1.5 TB/s. R4: 4096 blocks -> 83% occ but
//     4M cross-XCD colsum atomics added ~135 MB RMW traffic (WRITE_SIZE
//     5.6->100 MB), net wash at 169 us. R5: atomic-free — per-block
//     partial colsums (float4 stores) + tiny fold kernel.

#define EPS 1e-6f

constexpr int L   = 1024;
constexpr int DK  = 1024;
constexpr int DV  = 64;
constexpr int NBH = 64;           // B*H
constexpr int RPB = 32;           // rows per block (4 waves x 8 rows)
constexpr int NRB = L / RPB;      // 32 row-blocks per (b,h)

__device__ __forceinline__ float elup(float x) {
    // elu(x)+1 = x+1 (x>0), exp(x) (x<=0)
    return x > 0.0f ? x + 1.0f : __expf(x);
}

// Pass 1: stream Q,K once; rowsumQ/rowsumK per row; per-block colsum
// partials (no atomics). Grid 2048 -> 8 blocks/CU, 32 waves/CU.
template <bool ATOMIC>
__global__ __launch_bounds__(256, 8) void reduce_kernel(
    const float* __restrict__ Q, const float* __restrict__ K,
    float* __restrict__ colsum_or_partial, float* __restrict__ rowsumQ,
    float* __restrict__ rowsumK)
{
    const int bh   = blockIdx.x / NRB;
    const int rb   = blockIdx.x % NRB;
    const int wave = threadIdx.x >> 6;
    const int lane = threadIdx.x & 63;

    const size_t tile_base = (size_t)bh * L * DK;

    float4 cacc[4];
    #pragma unroll
    for (int i = 0; i < 4; ++i) cacc[i] = make_float4(0.f, 0.f, 0.f, 0.f);

    for (int j = 0; j < RPB / 4; ++j) {
        const int row = rb * RPB + wave * (RPB / 4) + j;
        const float* qp = Q + tile_base + (size_t)row * DK + lane * 4;
        const float* kp = K + tile_base + (size_t)row * DK + lane * 4;

        float4 q[4], k[4];
        #pragma unroll
        for (int i = 0; i < 4; ++i) q[i] = *(const float4*)(qp + i * 256);
        #pragma unroll
        for (int i = 0; i < 4; ++i) k[i] = *(const float4*)(kp + i * 256);

        float rq = 0.f, rk = 0.f;
        #pragma unroll
        for (int i = 0; i < 4; ++i) {
            const float q0 = elup(q[i].x), q1 = elup(q[i].y);
            const float q2 = elup(q[i].z), q3 = elup(q[i].w);
            const float k0 = elup(k[i].x), k1 = elup(k[i].y);
            const float k2 = elup(k[i].z), k3 = elup(k[i].w);
            rq += (q0 + q1) + (q2 + q3);
            rk += (k0 + k1) + (k2 + k3);
            cacc[i].x += k0; cacc[i].y += k1; cacc[i].z += k2; cacc[i].w += k3;
        }

        #pragma unroll
        for (int m = 32; m >= 1; m >>= 1) {
            rq += __shfl_xor(rq, m, 64);
            rk += __shfl_xor(rk, m, 64);
        }
        if (lane == 0) {
            rowsumQ[bh * L + row] = rq;
            rowsumK[bh * L + row] = rk;
        }
    }

    // Cross-wave column reduce in LDS: wave w dumps its 1024 partials to
    // slice w (float4, conflict-free); 256 threads fold the 4 slices as
    // float4 (2-way LDS aliasing = free) and store the block's partial
    // colsum with coalesced float4 stores (4 KB/block, no atomics).
    __shared__ float scol[4 * DK];
    #pragma unroll
    for (int i = 0; i < 4; ++i) {
        *(float4*)&scol[wave * DK + i * 256 + lane * 4] = cacc[i];
    }
    __syncthreads();
    const float4* scol4 = (const float4*)scol;
    const int t4 = threadIdx.x;                 // 256 float4s = 1024 floats
    float4 a = scol4[t4], b = scol4[256 + t4];
    float4 c = scol4[512 + t4], d = scol4[768 + t4];
    float4 s;
    s.x = (a.x + b.x) + (c.x + d.x);
    s.y = (a.y + b.y) + (c.y + d.y);
    s.z = (a.z + b.z) + (c.z + d.z);
    s.w = (a.w + b.w) + (c.w + d.w);
    if (ATOMIC) {
        float* cs = colsum_or_partial + bh * DK + t4 * 4;
        atomicAdd(cs + 0, s.x); atomicAdd(cs + 1, s.y);
        atomicAdd(cs + 2, s.z); atomicAdd(cs + 3, s.w);
    } else {
        ((float4*)colsum_or_partial)[(size_t)blockIdx.x * 256 + t4] = s;
    }
}

// Fold the 32 per-block partials of each (b,h) into colsum.
// 64 blocks x 256 threads; thread t4 owns 4 consecutive columns.
__global__ __launch_bounds__(256) void colsum_fold_kernel(
    const float* __restrict__ partial, float* __restrict__ colsum)
{
    const int bh = blockIdx.x;
    const int t4 = threadIdx.x;
    const float4* p4 = (const float4*)partial + (size_t)bh * NRB * 256 + t4;
    float4 acc = make_float4(0.f, 0.f, 0.f, 0.f);
    #pragma unroll 8
    for (int rb = 0; rb < NRB; ++rb) {
        const float4 v = p4[rb * 256];
        acc.x += v.x; acc.y += v.y; acc.z += v.z; acc.w += v.w;
    }
    ((float4*)colsum)[bh * 256 + t4] = acc;
}

// Pass 2: out = V * (rq*rk)/(rq*cs + EPS). One float4 per thread.
// colsum is indexed by l (k==l in this problem), so flat index == row.
__global__ __launch_bounds__(256) void finalize_kernel(
    const float* __restrict__ V, const float* __restrict__ colsum,
    const float* __restrict__ rowsumQ, const float* __restrict__ rowsumK,
    float* __restrict__ out)
{
    const int e4  = blockIdx.x * 256 + threadIdx.x; // group of 4 elems
    const int row = e4 >> 4;                        // DV/4 = 16 groups/row
    const float rq = rowsumQ[row];
    const float rk = rowsumK[row];
    const float cs = colsum[row];
    const float scale = rq * rk / (rq * cs + EPS);
    const float4 v = *(const float4*)(V + (size_t)e4 * 4);
    float4 o;
    o.x = v.x * scale; o.y = v.y * scale; o.z = v.z * scale; o.w = v.w * scale;
    *(float4*)(out + (size_t)e4 * 4) = o;
}

extern "C" void kernel_launch(void* const* d_in, const int* in_sizes, int n_in,
                              void* d_out, int out_size, void* d_ws, size_t ws_size,
                              hipStream_t stream) {
    const float* Q = (const float*)d_in[0];
    const float* K = (const float*)d_in[1];
    const float* V = (const float*)d_in[2];
    float* out = (float*)d_out;

    float* colsum  = (float*)d_ws;            // 64*1024 f32 = 256 KB
    float* rowsumQ = colsum + NBH * L;        // 256 KB
    float* rowsumK = rowsumQ + NBH * L;       // 256 KB
    float* partial = rowsumK + NBH * L;       // 2048*1024 f32 = 8 MB

    const size_t need = (size_t)(3 * NBH * L + NBH * NRB * DK) * sizeof(float);

    if (ws_size >= need) {
        // Atomic-free path.
        reduce_kernel<false><<<NBH * NRB, 256, 0, stream>>>(
            Q, K, partial, rowsumQ, rowsumK);
        colsum_fold_kernel<<<NBH, 256, 0, stream>>>(partial, colsum);
    } else {
        // Fallback: atomics into colsum (needs zero-init).
        hipMemsetAsync(colsum, 0, (size_t)NBH * DK * sizeof(float), stream);
        reduce_kernel<true><<<NBH * NRB, 256, 0, stream>>>(
            Q, K, colsum, rowsumQ, rowsumK);
    }

    finalize_kernel<<<(NBH * L * DV / 4) / 256, 256, 0, stream>>>(
        V, colsum, rowsumQ, rowsumK, out);
}